// Round 8
// baseline (353.790 us; speedup 1.0000x reference)
//
#include <hip/hip_runtime.h>

// HBV 2.0 fused scan + gamma-UH routing, MI355X (gfx950). Round 15.
// R14 (3-wave pipeline: snow | soil+gw | service) = 106.6us = 350 cy/step.
// Soil wave model: issue ~110 cy/step, serial chain ~180 (two pows in
// series); realized 350 => chain-bound with unfilled stall slots (during
// ef-pow latency there is no independent work left in the step).
// R15: 2 independent chains per lane. 64 cells/block (157 blocks), each
// lane runs BOTH nmul components of one cell: chain B's issue fills chain
// A's pow stalls (and shares P/T/E/dv reads; cross-m combine becomes a
// plain add in the conv wave). Same 3-wave 51-barrier pipeline; mod-4
// input buffers (27 DMA loads/chunk), [15][128] rts/Qt rings; vmcnt
// recounted so fresh stores are never force-drained:
//   prolog 27/27/27/42, steady 42 (= stores(n-3)[15]+loads(n+1)[27],
//   drains loads(n) + month-old stores), tail 30 (=2x15 stores) /0/0.
// Buffer lifetimes (interval k = (B_{k-1},B_k)): DMA(c) in k=c-1, snow(c)
// in k=c+1, soil(c) in k=c+2, conv(c) in k=c+3; buf c%4 re-DMA'd at
// k=c+3 > soil's last read. rb/qb mod-2 verified as in R14.
// Per-chain arithmetic textually identical to R14 -> bit-identical.

#define TS 730
#define NG 10000
#define CH 15
#define NCHUNK 49            // 49*15 = 735 >= 730
#define XSTRIDE (NG * 3)
#define DSTRIDE (NG * 4)
#define CELLS 64             // cells per block; 2 chains (m=0,1) per lane

#define AS1 __attribute__((address_space(1)))
#define AS3 __attribute__((address_space(3)))
// gfx9/CDNA s_waitcnt simm16: vmcnt[3:0]=simm[3:0], vmcnt[5:4]=simm[15:14],
// expcnt=simm[6:4], lgkmcnt=simm[11:8]
#define WAIT_VMCNT(n) __builtin_amdgcn_s_waitcnt(((n) & 15) | 0x70 | 0xF00 | (((n) >> 4) << 14))
#define WAIT_LGKM0    __builtin_amdgcn_s_waitcnt(0xC07F)
#define SBAR          __builtin_amdgcn_s_barrier
#define SCHED_FENCE() __builtin_amdgcn_sched_barrier(0)

__device__ __forceinline__ void gload16(const float* g, float* l) {
    __builtin_amdgcn_global_load_lds((const AS1 void*)g, (AS3 void*)l, 16, 0, 0);
}
// x^b for x>0 via native v_log_f32 + v_exp_f32
__device__ __forceinline__ float powpos(float x, float b) {
    return __builtin_amdgcn_exp2f(b * __builtin_amdgcn_logf(x));
}
// clamp(x, lo, hi) for lo<=hi, finite inputs: identical to min(max(x,lo),hi)
__device__ __forceinline__ float med3(float x, float lo, float hi) {
    return __builtin_amdgcn_fmed3f(x, lo, hi);
}

__global__ __launch_bounds__(192, 1) void hbv_fused(
    const float* __restrict__ x_phy,
    const float* __restrict__ ac_all,
    const float* __restrict__ params_dy,
    const float* __restrict__ params_stat,
    float* __restrict__ out)
{
    // LDS: mod-4 input buffers (linear DMA order) + [15][128] rings.
    // x chunk: 15 rows x 192 floats; 12 gload16/wave (720 units, pad->3072).
    // d chunk: 15 rows x 256 floats; 15 gload16/wave (960 units exact).
    __shared__ float xls0[3072], xls1[3072], xls2[3072], xls3[3072];
    __shared__ float dls0[3840], dls1[3840], dls2[3840], dls3[3840];
    __shared__ float rbA[1920], rbB[1920];   // rts: [15][m:2][lane:64]
    __shared__ float qbA[1920], qbB[1920];   // Qt : [15][m:2][lane:64]

    const int tid  = threadIdx.x;
    const int wid  = tid >> 6;             // 0=snow, 1=soil+gw, 2=service
    const int lane = tid & 63;             // lane == cell slot
    const int g0   = blockIdx.x * CELLS;
    // last block: shift 64-cell window left so staging never reads OOB
    const int g0r  = (g0 <= NG - CELLS) ? g0 : NG - CELLS;
    const int gcell = g0r + lane;          // this lane's global cell

    // per-cell param row (both m components live at [2i], [2i+1])
    const float* psl = params_stat + (size_t)gcell * 30;

    if (wid == 0) {
        // ======= wave 0: snow bucket, 2 chains/lane (m=0,1) =======
        float TTp[2], CFMAXv[2], nCFRC[2], CWHv[2], SP[2], MW[2];
#pragma unroll
        for (int mm = 0; mm < 2; ++mm) {
            TTp[mm]    = psl[14 + mm] * 5.f   - 2.5f;
            CFMAXv[mm] = psl[16 + mm] * 9.5f  + 0.5f;
            nCFRC[mm]  = -(psl[18 + mm] * 0.1f * CFMAXv[mm]);
            CWHv[mm]   = psl[20 + mm] * 0.2f;
            SP[mm] = 1e-3f; MW[mm] = 1e-3f;
        }
        auto snowc = [&](const float* xl, float* rbuf) {
            float Pc = xl[lane * 3 + 0], Tc = xl[lane * 3 + 1];
#pragma unroll
            for (int j = 0; j < CH; ++j) {
                float Pn, Tn;
                if (j < CH - 1) {
                    Pn = xl[(j + 1) * 192 + lane * 3 + 0];
                    Tn = xl[(j + 1) * 192 + lane * 3 + 1];
                }
#pragma unroll
                for (int mm = 0; mm < 2; ++mm) {
                    const float t1   = Tc - TTp[mm];
                    const float snow = (t1 < 0.f) ? Pc : 0.f;   // Tt < TTp
                    const float rain = Pc - snow;
                    SP[mm] += snow;
                    const float melt = med3(CFMAXv[mm] * t1, 0.f, SP[mm]);
                    MW[mm] += melt; SP[mm] -= melt;
                    const float refr = med3(nCFRC[mm] * t1, 0.f, MW[mm]);
                    SP[mm] += refr; MW[mm] -= refr;
                    const float tosoil = fmaxf(MW[mm] - CWHv[mm] * SP[mm], 0.f);
                    MW[mm] -= tosoil;
                    rbuf[(j << 7) + (mm << 6) + lane] = rain + tosoil;  // rts
                }
                Pc = Pn; Tc = Tn;
            }
        };
        SBAR();                                              // B_0
        for (int cq = 0; cq < 12; ++cq) {                    // chunks 0..47
            snowc(xls0, rbA); WAIT_LGKM0; SCHED_FENCE(); SBAR();
            snowc(xls1, rbB); WAIT_LGKM0; SCHED_FENCE(); SBAR();
            snowc(xls2, rbA); WAIT_LGKM0; SCHED_FENCE(); SBAR();
            snowc(xls3, rbB); WAIT_LGKM0; SCHED_FENCE(); SBAR();
        }
        snowc(xls0, rbA); WAIT_LGKM0; SCHED_FENCE(); SBAR(); // c=48, B_49
        SBAR();                                              // B_50
    } else if (wid == 1) {
        // ==== wave 1: soil + groundwater, 2 chains/lane (critical) ====
        float FCv[2], invFC[2], invLPFC[2], K0v[2], K1v[2], K2v[2],
              PERCv[2], UZLv[2], gwc[2], Ccv[2];
        float SM[2], SUZ[2], SLZ[2], CcSLZ[2];
        const float Acv = ac_all[gcell];
#pragma unroll
        for (int mm = 0; mm < 2; ++mm) {
            FCv[mm]   = psl[0  + mm] * 950.f  + 50.f;
            K0v[mm]   = psl[2  + mm] * 0.85f  + 0.05f;
            K1v[mm]   = psl[4  + mm] * 0.49f  + 0.01f;
            K2v[mm]   = psl[6  + mm] * 0.199f + 0.001f;
            const float LP = psl[8 + mm] * 0.8f + 0.2f;
            PERCv[mm] = psl[10 + mm] * 10.f;
            UZLv[mm]  = psl[12 + mm] * 100.f;
            Ccv[mm]   = psl[22 + mm];
            const float RT  = psl[24 + mm] * 20.f;
            const float ACp = psl[26 + mm] * 2500.f;
            invFC[mm]   = 1.f / FCv[mm];
            invLPFC[mm] = 1.f / (LP * FCv[mm]);
            gwc[mm] = RT * fminf(fmaxf(1.f - Acv / (ACp + 1e-5f), 0.f), 1.f);
            SM[mm] = 1e-3f; SUZ[mm] = 1e-3f; SLZ[mm] = 1e-3f;
            CcSLZ[mm] = Ccv[mm] * 1e-3f;     // == Cc*SLZ at step start
        }
        auto soilc = [&](const float* xl, const float* dl,
                         const float* rbuf, float* qbuf) {
            float Ec    = xl[lane * 3 + 2];
            float4 dvc  = *(const float4*)&dl[lane * 4];
            float rts0c = rbuf[lane], rts1c = rbuf[64 + lane];
#pragma unroll
            for (int j = 0; j < CH; ++j) {
                // next-step inputs at step top (full-step read-to-use)
                float En, rts0n, rts1n; float4 dvn;
                if (j < CH - 1) {
                    En    = xl[(j + 1) * 192 + lane * 3 + 2];
                    dvn   = *(const float4*)&dl[(j + 1) * 256 + lane * 4];
                    rts0n = rbuf[((j + 1) << 7) + lane];
                    rts1n = rbuf[((j + 1) << 7) + 64 + lane];
                }
                // two fully independent chains; compiler interleaves so
                // chain B's issue fills chain A's pow-latency stalls
#pragma unroll
                for (int mm = 0; mm < 2; ++mm) {
                    const float beta   = fmaf(mm ? dvc.y : dvc.x, 5.f, 1.f);
                    const float betaet = fmaf(mm ? dvc.w : dvc.z, 4.7f, 0.3f);
                    const float rts    = mm ? rts1c : rts0c;

                    const float sw = fminf(powpos(SM[mm] * invFC[mm], beta), 1.f);
                    SM[mm] = fmaf(rts, 1.f - sw, SM[mm]);
                    const float exc = fmaxf(SM[mm] - FCv[mm], 0.f);
                    SM[mm] = fminf(SM[mm], FCv[mm]);
                    const float ef = powpos(fminf(SM[mm] * invLPFC[mm], 1.f), betaet);
                    SM[mm] = fmaxf(SM[mm] - Ec * ef, 1e-5f);   // ET fuse, proven
                    const float cap = CcSLZ[mm] * fmaxf(1.f - SM[mm] * invFC[mm], 0.f);
                    SM[mm]  = fmaxf(SM[mm] + cap, 1e-5f);
                    SLZ[mm] = fmaxf(SLZ[mm] - cap, 1e-5f);

                    SUZ[mm] = SUZ[mm] + rts * sw + exc;
                    const float perc = fminf(SUZ[mm], PERCv[mm]);
                    SUZ[mm] -= perc;
                    const float Q0 = K0v[mm] * fmaxf(SUZ[mm] - UZLv[mm], 0.f);
                    SUZ[mm] -= Q0;
                    const float Q1 = K1v[mm] * SUZ[mm];
                    SUZ[mm] -= Q1;
                    SLZ[mm] += perc;
                    SLZ[mm] = fmaxf(SLZ[mm] - gwc[mm], 0.f);   // == -min(SLZ,gwcap)
                    const float Q2 = K2v[mm] * SLZ[mm];
                    SLZ[mm] -= Q2;
                    CcSLZ[mm] = Ccv[mm] * SLZ[mm];
                    qbuf[(j << 7) + (mm << 6) + lane] = Q0 + Q1 + Q2;
                }
                Ec = En; dvc = dvn; rts0c = rts0n; rts1c = rts1n;
            }
        };
        SBAR();                                              // B_0
        SBAR();                                              // B_1
        for (int cq = 0; cq < 12; ++cq) {                    // chunks 0..47
            soilc(xls0, dls0, rbA, qbA); WAIT_LGKM0; SCHED_FENCE(); SBAR();
            soilc(xls1, dls1, rbB, qbB); WAIT_LGKM0; SCHED_FENCE(); SBAR();
            soilc(xls2, dls2, rbA, qbA); WAIT_LGKM0; SCHED_FENCE(); SBAR();
            soilc(xls3, dls3, rbB, qbB); WAIT_LGKM0; SCHED_FENCE(); SBAR();
        }
        soilc(xls0, dls0, rbA, qbA); WAIT_LGKM0; SCHED_FENCE(); SBAR(); // B_50
    } else {
        // ====== wave 2: DMA engine + UH conv + stores (slack wave) ======
        const float ra  = psl[28] * 2.9f;
        const float rbp = psl[29] * 6.5f;
        const float a    = fmaxf(ra, 0.f) + 0.1f;
        const float th   = fmaxf(rbp, 0.f) + 0.5f;
        const float am1  = a - 1.f;
        const float nl2e = 1.44269504f / th;
        float w[CH];
        float wsum = 0.f;
#pragma unroll
        for (int k = 0; k < CH; ++k) {
            const float tk = (float)k + 0.5f;
            const float v  = __builtin_amdgcn_exp2f(am1 * __builtin_amdgcn_logf(tk) - tk * nl2e);
            w[k] = v; wsum += v;
        }
        const float wn = 0.5f / wsum;  // fold nmul-mean 0.5 into weights
#pragma unroll
        for (int k = 0; k < CH; ++k) w[k] *= wn;

        int offx[12], offd[15];
#pragma unroll
        for (int i = 0; i < 12; ++i) {
            int idx = i * 64 + lane; idx = idx < 720 ? idx : 719;
            const int row = idx / 48, col = idx - row * 48;   // 48 x 16B/row
            offx[i] = row * XSTRIDE + col * 4;
        }
#pragma unroll
        for (int i = 0; i < 15; ++i) {
            const int idx = i * 64 + lane;                    // 960 exact
            const int row = idx >> 6, col = idx & 63;
            offd[i] = row * DSTRIDE + col * 4;
        }
        const float* xbase = x_phy     + (size_t)g0r * 3;
        const float* dbase = params_dy + (size_t)g0r * 4;

        auto issue = [&](int cc, float* xl, float* dl) {  // 27 DMA ops
            if (cc == NCHUNK - 1) {
                // last chunk: rows 10..14 hit t=730..734 -> clamp abs t
#pragma unroll
                for (int i = 0; i < 12; ++i) {
                    int idx = i * 64 + lane; idx = idx < 720 ? idx : 719;
                    const int row = idx / 48, col = idx - row * 48;
                    int t = cc * CH + row; t = t < TS ? t : TS - 1;
                    gload16(xbase + (size_t)t * XSTRIDE + col * 4, xl + i * 256);
                }
#pragma unroll
                for (int i = 0; i < 15; ++i) {
                    const int idx = i * 64 + lane;
                    const int row = idx >> 6, col = idx & 63;
                    int t = cc * CH + row; t = t < TS ? t : TS - 1;
                    gload16(dbase + (size_t)t * DSTRIDE + col * 4, dl + i * 256);
                }
            } else {
                const float* xp = xbase + (size_t)cc * CH * XSTRIDE;
                const float* dp = dbase + (size_t)cc * CH * DSTRIDE;
#pragma unroll
                for (int i = 0; i < 12; ++i) gload16(xp + offx[i], xl + i * 256);
#pragma unroll
                for (int i = 0; i < 15; ++i) gload16(dp + offd[i], dl + i * 256);
            }
        };

        float facc[CH];
#pragma unroll
        for (int k = 0; k < CH; ++k) facc[k] = 0.f;
        // last block: slots < g0-g0r are duplicates of the previous block
        const bool doStore = (gcell >= g0);

        auto conv = [&](int c, const float* qb) {
            float* op = out + (size_t)c * CH * NG + gcell;
            const int tb = c * CH;
#pragma unroll
            for (int j = 0; j < CH; ++j) {
                // cross-m combine: plain add (0.5 folded into w)
                const float qm = qb[(j << 7) + lane] + qb[(j << 7) + 64 + lane];
#pragma unroll
                for (int k = 0; k < CH; ++k)
                    facc[(j + k) % CH] = fmaf(w[k], qm, facc[(j + k) % CH]);
                if (doStore && (tb + j < TS)) op[(size_t)j * NG] = facc[j];
                facc[j] = 0.f;               // recycle slot for t+15
            }
        };

        // prolog (interval k ends at B_k; wait drains loads(k+1)'s chunk)
        issue(0, xls0, dls0); issue(1, xls1, dls1);
        WAIT_VMCNT(27); SCHED_FENCE(); SBAR();               // B_0
        issue(2, xls2, dls2);
        WAIT_VMCNT(27); SCHED_FENCE(); SBAR();               // B_1
        issue(3, xls3, dls3);
        WAIT_VMCNT(27); SCHED_FENCE(); SBAR();               // B_2
        issue(4, xls0, dls0); conv(0, qbA);
        // outstanding: loads(3)[27], loads(4)[27], stores(0)[15]
        WAIT_VMCNT(42); SCHED_FENCE(); SBAR();               // B_3
        // steady n=4..47: issue(n+1); conv(n-3);
        // keep newest 42 = stores(n-3)[15] + loads(n+1)[27]; drains
        // loads(n) (required by snow at B_n) and stores(n-4) (ancient).
        for (int np = 0; np < 11; ++np) {
            const int n = 4 + 4 * np;
            issue(n + 1, xls1, dls1); conv(n - 3, qbB);
            WAIT_VMCNT(42); SCHED_FENCE(); SBAR();
            issue(n + 2, xls2, dls2); conv(n - 2, qbA);
            WAIT_VMCNT(42); SCHED_FENCE(); SBAR();
            issue(n + 3, xls3, dls3); conv(n - 1, qbB);
            WAIT_VMCNT(42); SCHED_FENCE(); SBAR();
            issue(n + 4, xls0, dls0); conv(n,     qbA);
            WAIT_VMCNT(42); SCHED_FENCE(); SBAR();
        }                                                    // ...B_47
        // interval 48: outstanding loads(48)[27], stores(44)[15], stores(45)[15]
        conv(45, qbB);
        WAIT_VMCNT(30); SCHED_FENCE(); SBAR();               // B_48
        conv(46, qbA); SBAR();                               // B_49
        conv(47, qbB); SBAR();                               // B_50
        conv(48, qbA);                                       // tail
    }
}

extern "C" void kernel_launch(void* const* d_in, const int* in_sizes, int n_in,
                              void* d_out, int out_size, void* d_ws, size_t ws_size,
                              hipStream_t stream) {
    const float* x_phy = (const float*)d_in[0];
    const float* ac    = (const float*)d_in[1];
    // d_in[2] = elev_all: unused by the reference forward
    const float* pdy   = (const float*)d_in[3];
    const float* pst   = (const float*)d_in[4];
    float* out = (float*)d_out;

    const int grid = (NG + CELLS - 1) / CELLS;  // 157 blocks x 3 waves
    hbv_fused<<<grid, 192, 0, stream>>>(x_phy, ac, pdy, pst, out);
}